// Round 9
// baseline (319.461 us; speedup 1.0000x reference)
//
#include <hip/hip_runtime.h>
#include <cstdint>
#include <cstddef>

#define HID    128
#define K1     385
#define NLAYER 4
#define NNODES 2048
#define NEDGES 129024
#define DEG    63
#define EPB    32               // edges per block
#define EBLOCKS (NEDGES / EPB)  // 4032
#define EA_STRIDE 256           // shorts per edge row aliased over f32 edge_attr row
#define NPB    16               // nodes per node-kernel block
#define NBLOCKS (NNODES / NPB)  // 128

// edge-kernel LDS byte map (EPB=32)
#define EIN_STRIDE 512          // 256 bf16 per row
#define HIDB    16384           // hid [32][256B]
#define MBASE   24576           // m   [32][256B]
#define REDBASE 32768           // 128 f32
#define RADBASE 33280           // 32 f32
#define HR1BASE 33408           // 256 f32 (hr1b: hr1 + b1, 2 nodes)
#define CB1BASE 34432           // 128 f32
#define CW2BASE 34944           // 128 f32
#define ELDS    35456

typedef __attribute__((ext_vector_type(8))) short short8;
typedef __attribute__((ext_vector_type(4))) float f32x4;

__device__ __forceinline__ unsigned pkbf(float a, float b) {
    unsigned r;
    asm("v_cvt_pk_bf16_f32 %0, %1, %2" : "=v"(r) : "v"(a), "v"(b));
    return r;   // low16 = bf16(a), high16 = bf16(b), RNE
}
__device__ __forceinline__ unsigned short f2bf(float a) {
    return (unsigned short)pkbf(a, a);
}
__device__ __forceinline__ float silu_f(float v) {
    return v * __builtin_amdgcn_rcpf(1.0f + __expf(-v));
}

// ---- unified weight packer: row-major f32 (K x 128) -> fragment-linear bf16
__global__ __launch_bounds__(64) void pack_all_kernel(
    const float* __restrict__ eW1, const float* __restrict__ eW2,
    const float* __restrict__ cW1, const float* __restrict__ nW1,
    const float* __restrict__ nW2,
    unsigned short* __restrict__ w1p, unsigned short* __restrict__ w1a,
    unsigned short* __restrict__ w2p, unsigned short* __restrict__ cw1p,
    unsigned short* __restrict__ nw1p, unsigned short* __restrict__ nw2p)
{
    int b = blockIdx.x;
    const float* src; unsigned short* dst; int KK, ls, mode;
    if (b < 256)      { src = eW1; dst = w1p;  KK = 8; ls = K1 * HID;      mode = 1; }
    else if (b < 384) { src = eW1; dst = w1a;  KK = 4; ls = K1 * HID;      mode = 0; b -= 256; }
    else if (b < 512) { src = eW2; dst = w2p;  KK = 4; ls = HID * HID;     mode = 0; b -= 384; }
    else if (b < 640) { src = cW1; dst = cw1p; KK = 4; ls = HID * HID;     mode = 0; b -= 512; }
    else if (b < 896) { src = nW1; dst = nw1p; KK = 8; ls = 2 * HID * HID; mode = 0; b -= 640; }
    else              { src = nW2; dst = nw2p; KK = 4; ls = HID * HID;     mode = 0; b -= 896; }
    const int tn = b & 7; b >>= 3;
    const int kk = b % KK;
    const int layer = b / KK;
    const int lane = threadIdx.x, lq = lane >> 4, lr = lane & 15;
    const float* s = src + (size_t)layer * ls;
    unsigned short* d = dst + (size_t)layer * (KK * 8 * 64 * 8)
                            + ((size_t)(kk * 8 + tn) * 64 + lane) * 8;
#pragma unroll
    for (int j = 0; j < 8; ++j) {
        const int kd = kk * 32 + lq * 8 + j;
        const int ka = mode ? (128 + kd + (kd >= 128 ? 1 : 0)) : kd;
        d[j] = f2bf(s[(size_t)ka * HID + tn * 16 + lr]);
    }
}

// embed + hr1b(layer0, incl. b1) + agg zero + x copy
__global__ __launch_bounds__(128) void embed_kernel(
    const float* __restrict__ h_in, const float* __restrict__ emb_w,
    const float* __restrict__ emb_b, const float* __restrict__ eW1,
    const float* __restrict__ eB1,
    float* __restrict__ h_ws, unsigned short* __restrict__ h_bf,
    float* __restrict__ hr1, float* __restrict__ agg,
    const float* __restrict__ x_in, float* __restrict__ x_a)
{
    const int n = blockIdx.x;
    const int o = threadIdx.x;
    __shared__ float hin[32];
    __shared__ float hrow[HID];
    if (o < 32) hin[o] = h_in[n * 32 + o];
    __syncthreads();
    float acc = emb_b[o];
#pragma unroll
    for (int k = 0; k < 32; ++k) acc += hin[k] * emb_w[k * HID + o];
    h_ws[n * HID + o] = acc;
    h_bf[n * HID + o] = f2bf(acc);
    hrow[o] = acc;
    agg[n * HID + o] = 0.0f;
    if (o < 3) x_a[n * 3 + o] = x_in[n * 3 + o];
    __syncthreads();
    float a2 = eB1[o];
    for (int k = 0; k < HID; ++k) a2 += hrow[k] * eW1[k * HID + o];
    hr1[n * HID + o] = a2;
}

// fused edge kernel (EPB=32, 512 threads)
__global__ __launch_bounds__(512, 6) void edge_mfma_kernel(
    const unsigned short* __restrict__ h_bf, const float* __restrict__ x,
    const float* __restrict__ ea_f32, unsigned short* __restrict__ ea,
    const int first_layer, const float* __restrict__ hr1,
    const short8* __restrict__ w1p, const float* __restrict__ w256,
    const short8* __restrict__ w2p, const float* __restrict__ b2,
    const short8* __restrict__ cw1p, const float* __restrict__ cb1, const float* __restrict__ cw2,
    float* __restrict__ c_out, float* __restrict__ agg)
{
    __shared__ __align__(16) char smem[ELDS];
    float* red    = (float*)(smem + REDBASE);
    float* radial = (float*)(smem + RADBASE);
    float* hr1s   = (float*)(smem + HR1BASE);
    float* cb1s   = (float*)(smem + CB1BASE);
    float* cw2s   = (float*)(smem + CW2BASE);
    const int t = threadIdx.x;
    const int w = t >> 6, lane = t & 63, lq = lane >> 4, lr = lane & 15;
    const int ebase = blockIdx.x * EPB;
    const int n0 = ebase / DEG;
    const int esplit = DEG * (n0 + 1) - ebase;  // rows >= esplit belong to n0+1 (may be >= EPB)

    // ---- staging: one row per 16 threads
    {
        const int s = t & 15, g = t >> 4;       // g = row 0..31
        const int r = g;
        const int e = ebase + r;
        const int row = n0 + (r >= esplit ? 1 : 0);
        const int jj = e - row * DEG;
        const int rl = row & 63;
        const int col = (row & ~63) + jj + (jj >= rl ? 1 : 0);
        const int swz = (r & 7) << 4;
        *(uint4*)(smem + r * EIN_STRIDE + ((s * 16) ^ swz)) =
            *(const uint4*)(h_bf + (size_t)col * HID + s * 8);
        uint4 v;
        if (first_layer) {
            const float4* ef = (const float4*)(ea_f32 + (size_t)e * HID);
            const float4 f0 = ef[s * 2], f1 = ef[s * 2 + 1];
            v.x = pkbf(f0.x, f0.y);
            v.y = pkbf(f0.z, f0.w);
            v.z = pkbf(f1.x, f1.y);
            v.w = pkbf(f1.z, f1.w);
        } else {
            v = *(const uint4*)(ea + (size_t)e * EA_STRIDE + s * 8);
        }
        *(uint4*)(smem + r * EIN_STRIDE + (((s + 16) * 16) ^ swz)) = v;
        if (s == 0) {
            const float dx = x[row * 3 + 0] - x[col * 3 + 0];
            const float dy = x[row * 3 + 1] - x[col * 3 + 1];
            const float dz = x[row * 3 + 2] - x[col * 3 + 2];
            radial[r] = dx * dx + dy * dy + dz * dz;
        }
        if (t < 128) { cb1s[t] = cb1[t]; cw2s[t] = cw2[t]; }
        else if (t < 384) {
            const int i2 = t - 128;
            hr1s[i2] = hr1[(size_t)(n0 + (i2 >> 7)) * HID + (i2 & 127)];
        }
    }
    __syncthreads();

    const int c0 = w * 16 + lr;

    // ---- GEMM1: einA(32x256) @ W1' ; wave w owns cols [w*16, w*16+16)
    f32x4 acc1[2] = {};
#pragma unroll
    for (int kk = 0; kk < 8; ++kk) {
        const short8 bf = w1p[(kk * 8 + w) * 64 + lane];
#pragma unroll
        for (int mt = 0; mt < 2; ++mt) {
            const int r = mt * 16 + lr;
            const short8 af = *(const short8*)(smem + r * EIN_STRIDE +
                                ((kk * 64 + lq * 16) ^ ((r & 7) << 4)));
            acc1[mt] = __builtin_amdgcn_mfma_f32_16x16x32_bf16(af, bf, acc1[mt], 0, 0, 0);
        }
    }
    // ---- epilogue 1 -> hid (own region, no barrier needed vs GEMM1 readers)
    {
        const float ww = w256[c0];
        const float ha = hr1s[c0], hb = hr1s[128 + c0];
#pragma unroll
        for (int mt = 0; mt < 2; ++mt)
#pragma unroll
            for (int reg = 0; reg < 4; ++reg) {
                const int r = mt * 16 + lq * 4 + reg;
                const float v = silu_f(acc1[mt][reg] + radial[r] * ww +
                                       (r < esplit ? ha : hb));
                *(unsigned short*)(smem + HIDB + r * 256 + ((c0 * 2) ^ ((r & 7) << 4))) = f2bf(v);
            }
    }
    __syncthreads();

    // ---- GEMM2: hid(32x128) @ W2
    f32x4 acc2[2] = {};
#pragma unroll
    for (int kk = 0; kk < 4; ++kk) {
        const short8 bf = w2p[(kk * 8 + w) * 64 + lane];
#pragma unroll
        for (int mt = 0; mt < 2; ++mt) {
            const int r = mt * 16 + lr;
            const short8 af = *(const short8*)(smem + HIDB + r * 256 +
                                ((kk * 64 + lq * 16) ^ ((r & 7) << 4)));
            acc2[mt] = __builtin_amdgcn_mfma_f32_16x16x32_bf16(af, bf, acc2[mt], 0, 0, 0);
        }
    }
    // ---- epilogue 2: m = silu(acc2+b2) -> LDS + per-node column sums (agg)
    {
        const float bb = b2[c0];
        float s0 = 0.0f, s1 = 0.0f;
#pragma unroll
        for (int mt = 0; mt < 2; ++mt)
#pragma unroll
            for (int reg = 0; reg < 4; ++reg) {
                const int r = mt * 16 + lq * 4 + reg;
                const float v = silu_f(acc2[mt][reg] + bb);
                if (r < esplit) s0 += v; else s1 += v;
                *(unsigned short*)(smem + MBASE + r * 256 + ((c0 * 2) ^ ((r & 7) << 4))) = f2bf(v);
            }
        s0 += __shfl_xor(s0, 16); s0 += __shfl_xor(s0, 32);
        s1 += __shfl_xor(s1, 16); s1 += __shfl_xor(s1, 32);
        if (lane < 16) {
            atomicAdd(&agg[(size_t)n0 * HID + c0], s0);
            if (esplit < EPB)
                atomicAdd(&agg[(size_t)(n0 + 1) * HID + c0], s1);
        }
    }
    __syncthreads();

    // ---- GEMM3 (transposed): D[j2][e] = cW1^T @ m^T
    // wave w: etile = w&1 (16 edges), jquarter = w>>1 (32 j2 rows)
    const int etile = w & 1, jq = w >> 1;
    f32x4 acc3[2] = {};
    {
        const int erow = etile * 16 + lr;
        const int eswz = (erow & 7) << 4;
#pragma unroll
        for (int kb = 0; kb < 4; ++kb) {
            const short8 mf = *(const short8*)(smem + MBASE + erow * 256 +
                                ((kb * 64 + lq * 16) ^ eswz));
#pragma unroll
            for (int jt = 0; jt < 2; ++jt) {
                const short8 af = cw1p[(kb * 8 + jq * 2 + jt) * 64 + lane];
                acc3[jt] = __builtin_amdgcn_mfma_f32_16x16x32_bf16(af, mf, acc3[jt], 0, 0, 0);
            }
        }
    }
    // ---- m -> global (bf16, row-contiguous from LDS)
    {
        const int s = t & 15, g = t >> 4;
        const uint4 v = *(const uint4*)(smem + MBASE + g * 256 +
                                        ((s * 16) ^ ((g & 7) << 4)));
        *(uint4*)(ea + (size_t)(ebase + g) * EA_STRIDE + s * 8) = v;
    }
    // ---- epilogue 3: per-lane dot over its 8 j2 rows, 2 shfl, 1 LDS write
    {
        float p = 0.0f;
#pragma unroll
        for (int jt = 0; jt < 2; ++jt)
#pragma unroll
            for (int reg = 0; reg < 4; ++reg) {
                const int j2 = jq * 32 + jt * 16 + lq * 4 + reg;
                p += silu_f(acc3[jt][reg] + cb1s[j2]) * cw2s[j2];
            }
        p += __shfl_xor(p, 16);
        p += __shfl_xor(p, 32);
        if (lane < 16) red[jq * 32 + etile * 16 + lane] = p;
    }
    __syncthreads();
    if (t < 32) c_out[ebase + t] = red[t] + red[32 + t] + red[64 + t] + red[96 + t];
}

// node kernel: [h|agg] MLP (MFMA, residual) + agg re-zero + coord update
// + next-layer hr1b = hnew @ W1a + b1_next
__global__ __launch_bounds__(512, 4) void node_mfma_kernel(
    float* __restrict__ h_ws, unsigned short* __restrict__ h_bf,
    float* __restrict__ agg,
    const short8* __restrict__ nw1p, const float* __restrict__ nb1,
    const short8* __restrict__ nw2p, const float* __restrict__ nb2,
    const short8* __restrict__ w1a_next, const float* __restrict__ b1_next,
    float* __restrict__ hr1,
    const float* __restrict__ x_in, float* __restrict__ x_out,
    const float* __restrict__ c_ws,
    float* __restrict__ out, const int write_out, const int do_coord)
{
    __shared__ __align__(16) char smem[16384];  // nin[16][512B] | hid@8192 | hnew@12288
    const int t = threadIdx.x;
    const int w = t >> 6, lane = t & 63, lq = lane >> 4, lr = lane & 15;
    const int nb = blockIdx.x * NPB;

    // ---- stage nin = [h | agg] (16 rows x 32 slots), zero agg
    {
        const int s = t & 31, g = t >> 5;       // g = row 0..15
        const int node = nb + g;
        const int swz = (g & 7) << 4;
        if (s < 16) {
            *(uint4*)(smem + g * 512 + ((s * 16) ^ swz)) =
                *(const uint4*)(h_bf + (size_t)node * HID + s * 8);
        } else {
            const int q = s - 16;
            float4* agg4 = (float4*)(agg + (size_t)node * HID);
            const float4 a0 = agg4[q * 2], a1 = agg4[q * 2 + 1];
            agg4[q * 2]     = float4{0, 0, 0, 0};
            agg4[q * 2 + 1] = float4{0, 0, 0, 0};
            uint4 v;
            v.x = pkbf(a0.x, a0.y);
            v.y = pkbf(a0.z, a0.w);
            v.z = pkbf(a1.x, a1.y);
            v.w = pkbf(a1.z, a1.w);
            *(uint4*)(smem + g * 512 + ((s * 16) ^ swz)) = v;
        }
    }
    __syncthreads();

    const int c0 = w * 16 + lr;

    // ---- GEMM1: nin(16x256) @ nW1
    f32x4 acc1 = {};
#pragma unroll
    for (int kk = 0; kk < 8; ++kk) {
        const short8 bf = nw1p[(kk * 8 + w) * 64 + lane];
        const short8 af = *(const short8*)(smem + lr * 512 +
                            ((kk * 64 + lq * 16) ^ ((lr & 7) << 4)));
        acc1 = __builtin_amdgcn_mfma_f32_16x16x32_bf16(af, bf, acc1, 0, 0, 0);
    }
    __syncthreads();
    {
        const float bb = nb1[c0];
#pragma unroll
        for (int reg = 0; reg < 4; ++reg) {
            const int r = lq * 4 + reg;
            const float v = silu_f(acc1[reg] + bb);
            *(unsigned short*)(smem + 8192 + r * 256 + ((c0 * 2) ^ ((r & 7) << 4))) = f2bf(v);
        }
    }
    __syncthreads();
    // ---- GEMM2: hid(16x128) @ nW2
    f32x4 acc2 = {};
#pragma unroll
    for (int kk = 0; kk < 4; ++kk) {
        const short8 bf = nw2p[(kk * 8 + w) * 64 + lane];
        const short8 af = *(const short8*)(smem + 8192 + lr * 256 +
                            ((kk * 64 + lq * 16) ^ ((lr & 7) << 4)));
        acc2 = __builtin_amdgcn_mfma_f32_16x16x32_bf16(af, bf, acc2, 0, 0, 0);
    }
    // ---- epilogue 2: residual; write h (f32/bf16/out); stage hnew
    {
        const float bb = nb2[c0];
#pragma unroll
        for (int reg = 0; reg < 4; ++reg) {
            const int r = lq * 4 + reg;
            const size_t gi = (size_t)(nb + r) * HID + c0;
            const float hnew = h_ws[gi] + acc2[reg] + bb;
            h_ws[gi] = hnew;
            h_bf[gi] = f2bf(hnew);
            if (write_out) out[gi] = hnew;
            *(unsigned short*)(smem + 12288 + r * 256 + ((c0 * 2) ^ ((r & 7) << 4))) = f2bf(hnew);
        }
    }
    __syncthreads();
    // ---- hr1b for next layer: hnew(16x128) @ W1a_next + b1_next
    if (w1a_next) {
        f32x4 acch = {};
#pragma unroll
        for (int kk = 0; kk < 4; ++kk) {
            const short8 bf = w1a_next[(kk * 8 + w) * 64 + lane];
            const short8 af = *(const short8*)(smem + 12288 + lr * 256 +
                                ((kk * 64 + lq * 16) ^ ((lr & 7) << 4)));
            acch = __builtin_amdgcn_mfma_f32_16x16x32_bf16(af, bf, acch, 0, 0, 0);
        }
        const float bb = b1_next[c0];
#pragma unroll
        for (int reg = 0; reg < 4; ++reg) {
            const int r = lq * 4 + reg;
            hr1[(size_t)(nb + r) * HID + c0] = acch[reg] + bb;
        }
    }
    // ---- coordinate update
    if (do_coord) {
        const int nl = t >> 5, sub = t & 31;
        const int n = nb + nl;
        const int rl = n & 63, base = n & ~63;
        const float xi0 = x_in[n * 3 + 0], xi1 = x_in[n * 3 + 1], xi2 = x_in[n * 3 + 2];
        float p0 = 0, p1 = 0, p2 = 0;
#pragma unroll
        for (int kk = 0; kk < 2; ++kk) {
            const int k = sub + kk * 32;
            if (k < DEG) {
                const int e = n * DEG + k;
                const int col = base + k + (k >= rl ? 1 : 0);
                const float c = c_ws[e];
                p0 += c * (xi0 - x_in[col * 3 + 0]);
                p1 += c * (xi1 - x_in[col * 3 + 1]);
                p2 += c * (xi2 - x_in[col * 3 + 2]);
            }
        }
#pragma unroll
        for (int off = 1; off < 32; off <<= 1) {
            p0 += __shfl_xor(p0, off);
            p1 += __shfl_xor(p1, off);
            p2 += __shfl_xor(p2, off);
        }
        if (sub == 0) {
            const float inv = 1.0f / DEG;
            x_out[n * 3 + 0] = xi0 + p0 * inv;
            x_out[n * 3 + 1] = xi1 + p1 * inv;
            x_out[n * 3 + 2] = xi2 + p2 * inv;
        }
    }
}

extern "C" void kernel_launch(void* const* d_in, const int* in_sizes, int n_in,
                              void* d_out, int out_size, void* d_ws, size_t ws_size,
                              hipStream_t stream)
{
    const float* h_in  = (const float*)d_in[0];
    const float* x_in  = (const float*)d_in[1];
    const float* ea0   = (const float*)d_in[4];
    const float* emb_w = (const float*)d_in[5];
    const float* emb_b = (const float*)d_in[6];
    const float* eW1   = (const float*)d_in[7];
    const float* eB1   = (const float*)d_in[8];
    const float* eW2   = (const float*)d_in[9];
    const float* eB2   = (const float*)d_in[10];
    const float* nW1   = (const float*)d_in[11];
    const float* nB1   = (const float*)d_in[12];
    const float* nW2   = (const float*)d_in[13];
    const float* nB2   = (const float*)d_in[14];
    const float* cW1   = (const float*)d_in[15];
    const float* cB1   = (const float*)d_in[16];
    const float* cW2   = (const float*)d_in[17];
    float* out = (float*)d_out;

    // bf16 edge features aliased over f32 edge_attr (256B used of each 512B row;
    // per-edge byte ranges coincide -> block-local in-place conversion, no race)
    unsigned short* ea_bf = (unsigned short*)d_in[4];

    char* p = (char*)d_ws;
    float* h_ws = (float*)p;                    p += (size_t)NNODES * HID * 4;
    unsigned short* h_bf = (unsigned short*)p;  p += (size_t)NNODES * HID * 2;
    float* agg  = (float*)p;                    p += (size_t)(NNODES + 1) * HID * 4;
    float* hr1  = (float*)p;                    p += (size_t)(NNODES + 1) * HID * 4;  // +1 pad: tail block prefetches hr1[2048]
    float* x_a  = (float*)p;                    p += NNODES * 3 * 4 + 16;
    float* x_b  = (float*)p;                    p += NNODES * 3 * 4 + 16;
    float* c_ws = (float*)p;                    p += (size_t)NEDGES * 4;
    unsigned short* w1p  = (unsigned short*)p;  p += (size_t)NLAYER * 8 * 8 * 64 * 8 * 2;
    unsigned short* w1a  = (unsigned short*)p;  p += (size_t)NLAYER * 4 * 8 * 64 * 8 * 2;
    unsigned short* w2p  = (unsigned short*)p;  p += (size_t)NLAYER * 4 * 8 * 64 * 8 * 2;
    unsigned short* cw1p = (unsigned short*)p;  p += (size_t)NLAYER * 4 * 8 * 64 * 8 * 2;
    unsigned short* nw1p = (unsigned short*)p;  p += (size_t)NLAYER * 8 * 8 * 64 * 8 * 2;
    unsigned short* nw2p = (unsigned short*)p;  p += (size_t)NLAYER * 4 * 8 * 64 * 8 * 2;

    const int SL8 = 8 * 8 * 64 * 8;
    const int SL4 = 4 * 8 * 64 * 8;

    pack_all_kernel<<<1024, 64, 0, stream>>>(eW1, eW2, cW1, nW1, nW2,
                                             w1p, w1a, w2p, cw1p, nw1p, nw2p);

    embed_kernel<<<NNODES, HID, 0, stream>>>(h_in, emb_w, emb_b, eW1, eB1,
                                             h_ws, h_bf, hr1, agg, x_in, x_a);

    float* xc = x_a;
    float* xn = x_b;
    for (int i = 0; i < NLAYER; ++i) {
        edge_mfma_kernel<<<EBLOCKS, 512, 0, stream>>>(
            h_bf, xc, ea0, ea_bf, (i == 0) ? 1 : 0, hr1,
            (const short8*)(w1p + (size_t)i * SL8),
            eW1 + ((size_t)i * K1 + 256) * HID,
            (const short8*)(w2p + (size_t)i * SL4), eB2 + i * HID,
            (const short8*)(cw1p + (size_t)i * SL4), cB1 + i * HID,
            cW2 + (size_t)i * HID, c_ws, agg);
        node_mfma_kernel<<<NBLOCKS, 512, 0, stream>>>(
            h_ws, h_bf, agg,
            (const short8*)(nw1p + (size_t)i * SL8), nB1 + i * HID,
            (const short8*)(nw2p + (size_t)i * SL4), nB2 + i * HID,
            (i < NLAYER - 1) ? (const short8*)(w1a + (size_t)(i + 1) * SL4) : (const short8*)nullptr,
            (i < NLAYER - 1) ? (eB1 + (size_t)(i + 1) * HID) : nullptr,
            hr1, xc, xn, c_ws,
            out, (i == NLAYER - 1) ? 1 : 0, (i < NLAYER - 1) ? 1 : 0);
        float* tmp = xc; xc = xn; xn = tmp;
    }
}

// Round 10
// 299.288 us; speedup vs baseline: 1.0674x; 1.0674x over previous
//
#include <hip/hip_runtime.h>
#include <cstdint>
#include <cstddef>

#define HID    128
#define K1     385
#define NLAYER 4
#define NNODES 2048
#define NEDGES 129024
#define DEG    63
#define EPB    64               // edges per block (measured best)
#define EBLOCKS (NEDGES / EPB)  // 2016
#define EA_STRIDE 256           // shorts per edge row aliased over f32 edge_attr row
#define NPB    16               // nodes per node-kernel block
#define NBLOCKS (NNODES / NPB)  // 128

// edge-kernel LDS byte map (EPB=64)
#define EIN_STRIDE 512          // 256 bf16 per row; hid overlays [0,16384) after GEMM1
#define MBASE   16384           // m [64][256B]
#define REDBASE 32768           // 128 f32
#define RADBASE 33280           // 64 f32
#define DXBASE  33536           // 64 f32
#define DYBASE  33792           // 64 f32
#define DZBASE  34048           // 64 f32
#define HR1BASE 34304           // 256 f32 (hr1b: hr1 + b1, 2 nodes)
#define CB1BASE 35328           // 128 f32
#define CW2BASE 35840           // 128 f32
#define ELDS    36352

typedef __attribute__((ext_vector_type(8))) short short8;
typedef __attribute__((ext_vector_type(4))) float f32x4;

__device__ __forceinline__ unsigned pkbf(float a, float b) {
    unsigned r;
    asm("v_cvt_pk_bf16_f32 %0, %1, %2" : "=v"(r) : "v"(a), "v"(b));
    return r;   // low16 = bf16(a), high16 = bf16(b), RNE
}
__device__ __forceinline__ unsigned short f2bf(float a) {
    return (unsigned short)pkbf(a, a);
}
__device__ __forceinline__ float silu_f(float v) {
    return v * __builtin_amdgcn_rcpf(1.0f + __expf(-v));
}

// ---- unified weight packer: row-major f32 (K x 128) -> fragment-linear bf16
__global__ __launch_bounds__(64) void pack_all_kernel(
    const float* __restrict__ eW1, const float* __restrict__ eW2,
    const float* __restrict__ cW1, const float* __restrict__ nW1,
    const float* __restrict__ nW2,
    unsigned short* __restrict__ w1p, unsigned short* __restrict__ w1a,
    unsigned short* __restrict__ w2p, unsigned short* __restrict__ cw1p,
    unsigned short* __restrict__ nw1p, unsigned short* __restrict__ nw2p)
{
    int b = blockIdx.x;
    const float* src; unsigned short* dst; int KK, ls, mode;
    if (b < 256)      { src = eW1; dst = w1p;  KK = 8; ls = K1 * HID;      mode = 1; }
    else if (b < 384) { src = eW1; dst = w1a;  KK = 4; ls = K1 * HID;      mode = 0; b -= 256; }
    else if (b < 512) { src = eW2; dst = w2p;  KK = 4; ls = HID * HID;     mode = 0; b -= 384; }
    else if (b < 640) { src = cW1; dst = cw1p; KK = 4; ls = HID * HID;     mode = 0; b -= 512; }
    else if (b < 896) { src = nW1; dst = nw1p; KK = 8; ls = 2 * HID * HID; mode = 0; b -= 640; }
    else              { src = nW2; dst = nw2p; KK = 4; ls = HID * HID;     mode = 0; b -= 896; }
    const int tn = b & 7; b >>= 3;
    const int kk = b % KK;
    const int layer = b / KK;
    const int lane = threadIdx.x, lq = lane >> 4, lr = lane & 15;
    const float* s = src + (size_t)layer * ls;
    unsigned short* d = dst + (size_t)layer * (KK * 8 * 64 * 8)
                            + ((size_t)(kk * 8 + tn) * 64 + lane) * 8;
#pragma unroll
    for (int j = 0; j < 8; ++j) {
        const int kd = kk * 32 + lq * 8 + j;
        const int ka = mode ? (128 + kd + (kd >= 128 ? 1 : 0)) : kd;
        d[j] = f2bf(s[(size_t)ka * HID + tn * 16 + lr]);
    }
}

// embed + hr1b(layer0, incl. b1) + agg/xdelta zero + x copy
__global__ __launch_bounds__(128) void embed_kernel(
    const float* __restrict__ h_in, const float* __restrict__ emb_w,
    const float* __restrict__ emb_b, const float* __restrict__ eW1,
    const float* __restrict__ eB1,
    float* __restrict__ h_ws, unsigned short* __restrict__ h_bf,
    float* __restrict__ hr1, float* __restrict__ agg, float* __restrict__ xdelta,
    const float* __restrict__ x_in, float* __restrict__ x_a)
{
    const int n = blockIdx.x;
    const int o = threadIdx.x;
    __shared__ float hin[32];
    __shared__ float hrow[HID];
    if (o < 32) hin[o] = h_in[n * 32 + o];
    __syncthreads();
    float acc = emb_b[o];
#pragma unroll
    for (int k = 0; k < 32; ++k) acc += hin[k] * emb_w[k * HID + o];
    h_ws[n * HID + o] = acc;
    h_bf[n * HID + o] = f2bf(acc);
    hrow[o] = acc;
    agg[n * HID + o] = 0.0f;
    if (o < 3) { x_a[n * 3 + o] = x_in[n * 3 + o]; xdelta[n * 3 + o] = 0.0f; }
    __syncthreads();
    float a2 = eB1[o];
    for (int k = 0; k < HID; ++k) a2 += hrow[k] * eW1[k * HID + o];
    hr1[n * HID + o] = a2;
}

// fused edge kernel (EPB=64, 512 threads)
__global__ __launch_bounds__(512, 6) void edge_mfma_kernel(
    const unsigned short* __restrict__ h_bf, const float* __restrict__ x,
    const float* __restrict__ ea_f32, unsigned short* __restrict__ ea,
    const int first_layer, const float* __restrict__ hr1,
    const short8* __restrict__ w1p, const float* __restrict__ w256,
    const short8* __restrict__ w2p, const float* __restrict__ b2,
    const short8* __restrict__ cw1p, const float* __restrict__ cb1, const float* __restrict__ cw2,
    float* __restrict__ xdelta,     // nullptr on last layer -> skip GEMM3/coord/m-write
    float* __restrict__ agg)
{
    __shared__ __align__(16) char smem[ELDS];
    float* red    = (float*)(smem + REDBASE);
    float* radial = (float*)(smem + RADBASE);
    float* dxs    = (float*)(smem + DXBASE);
    float* dys    = (float*)(smem + DYBASE);
    float* dzs    = (float*)(smem + DZBASE);
    float* hr1s   = (float*)(smem + HR1BASE);
    float* cb1s   = (float*)(smem + CB1BASE);
    float* cw2s   = (float*)(smem + CW2BASE);
    const int t = threadIdx.x;
    const int w = t >> 6, lane = t & 63, lq = lane >> 4, lr = lane & 15;
    const int ebase = blockIdx.x * EPB;
    const int n0 = ebase / DEG;
    const int esplit = DEG * (n0 + 1) - ebase;  // in [1,63]: rows >= esplit belong to n0+1

    // ---- staging: 16 lanes cover one row's 32 slots (2 rows per 32 threads)
    {
        const int s = t & 15, g = t >> 4;       // g in 0..31
#pragma unroll
        for (int j = 0; j < 2; ++j) {
            const int r = g + j * 32;
            const int e = ebase + r;
            const int row = n0 + (r >= esplit ? 1 : 0);
            const int jj = e - row * DEG;
            const int rl = row & 63;
            const int col = (row & ~63) + jj + (jj >= rl ? 1 : 0);
            const int swz = (r & 7) << 4;
            *(uint4*)(smem + r * EIN_STRIDE + ((s * 16) ^ swz)) =
                *(const uint4*)(h_bf + (size_t)col * HID + s * 8);
            uint4 v;
            if (first_layer) {
                const float4* ef = (const float4*)(ea_f32 + (size_t)e * HID);
                const float4 f0 = ef[s * 2], f1 = ef[s * 2 + 1];
                v.x = pkbf(f0.x, f0.y);
                v.y = pkbf(f0.z, f0.w);
                v.z = pkbf(f1.x, f1.y);
                v.w = pkbf(f1.z, f1.w);
            } else {
                v = *(const uint4*)(ea + (size_t)e * EA_STRIDE + s * 8);
            }
            *(uint4*)(smem + r * EIN_STRIDE + (((s + 16) * 16) ^ swz)) = v;
            if (s == 0) {
                const float dx = x[row * 3 + 0] - x[col * 3 + 0];
                const float dy = x[row * 3 + 1] - x[col * 3 + 1];
                const float dz = x[row * 3 + 2] - x[col * 3 + 2];
                radial[r] = dx * dx + dy * dy + dz * dz;
                dxs[r] = dx; dys[r] = dy; dzs[r] = dz;
            }
        }
        if (t < 128) { cb1s[t] = cb1[t]; cw2s[t] = cw2[t]; }
        else if (t < 384) {
            const int i2 = t - 128;
            hr1s[i2] = hr1[(size_t)(n0 + (i2 >> 7)) * HID + (i2 & 127)];
        }
    }
    __syncthreads();

    const int c0 = w * 16 + lr;

    // ---- GEMM1: einA(64x256) @ W1' ; wave w owns cols [w*16, w*16+16)
    // addr split: (kk*64+lq*16)^swz == kk2*128 + ((parity*64+lq*16)^swz)  (bit-disjoint)
    f32x4 acc1[4] = {};
#pragma unroll
    for (int kk2 = 0; kk2 < 4; ++kk2) {
        const short8 bf0 = w1p[((2 * kk2) * 8 + w) * 64 + lane];
        const short8 bf1 = w1p[((2 * kk2 + 1) * 8 + w) * 64 + lane];
#pragma unroll
        for (int mt = 0; mt < 4; ++mt) {
            const int r = mt * 16 + lr;
            const int swz = (r & 7) << 4;
            const char* b0 = smem + r * EIN_STRIDE + ((lq * 16) ^ swz);
            const char* b1 = smem + r * EIN_STRIDE + ((lq * 16 + 64) ^ swz);
            acc1[mt] = __builtin_amdgcn_mfma_f32_16x16x32_bf16(
                *(const short8*)(b0 + kk2 * 128), bf0, acc1[mt], 0, 0, 0);
            acc1[mt] = __builtin_amdgcn_mfma_f32_16x16x32_bf16(
                *(const short8*)(b1 + kk2 * 128), bf1, acc1[mt], 0, 0, 0);
        }
    }
    __syncthreads();   // einA dead; hid overlays base 0

    // ---- epilogue 1: hid = silu(acc + radial*w256 + hr1b[node])
    {
        const float ww = w256[c0];
        const float ha = hr1s[c0], hb = hr1s[128 + c0];
#pragma unroll
        for (int mt = 0; mt < 4; ++mt)
#pragma unroll
            for (int reg = 0; reg < 4; ++reg) {
                const int r = mt * 16 + lq * 4 + reg;
                const float v = silu_f(acc1[mt][reg] + radial[r] * ww +
                                       (r < esplit ? ha : hb));
                *(unsigned short*)(smem + r * 256 + ((c0 * 2) ^ ((r & 7) << 4))) = f2bf(v);
            }
    }
    __syncthreads();

    // ---- GEMM2: hid(64x128) @ W2
    f32x4 acc2[4] = {};
#pragma unroll
    for (int kk2 = 0; kk2 < 2; ++kk2) {
        const short8 bf0 = w2p[((2 * kk2) * 8 + w) * 64 + lane];
        const short8 bf1 = w2p[((2 * kk2 + 1) * 8 + w) * 64 + lane];
#pragma unroll
        for (int mt = 0; mt < 4; ++mt) {
            const int r = mt * 16 + lr;
            const int swz = (r & 7) << 4;
            const char* b0 = smem + r * 256 + ((lq * 16) ^ swz);
            const char* b1 = smem + r * 256 + ((lq * 16 + 64) ^ swz);
            acc2[mt] = __builtin_amdgcn_mfma_f32_16x16x32_bf16(
                *(const short8*)(b0 + kk2 * 128), bf0, acc2[mt], 0, 0, 0);
            acc2[mt] = __builtin_amdgcn_mfma_f32_16x16x32_bf16(
                *(const short8*)(b1 + kk2 * 128), bf1, acc2[mt], 0, 0, 0);
        }
    }
    // ---- epilogue 2: m = silu(acc2+b2) -> LDS + per-node column sums (agg)
    {
        const float bb = b2[c0];
        float s0 = 0.0f, s1 = 0.0f;
#pragma unroll
        for (int mt = 0; mt < 4; ++mt)
#pragma unroll
            for (int reg = 0; reg < 4; ++reg) {
                const int r = mt * 16 + lq * 4 + reg;
                const float v = silu_f(acc2[mt][reg] + bb);
                if (r < esplit) s0 += v; else s1 += v;
                *(unsigned short*)(smem + MBASE + r * 256 + ((c0 * 2) ^ ((r & 7) << 4))) = f2bf(v);
            }
        s0 += __shfl_xor(s0, 16); s0 += __shfl_xor(s0, 32);
        s1 += __shfl_xor(s1, 16); s1 += __shfl_xor(s1, 32);
        if (lane < 16) {
            atomicAdd(&agg[(size_t)n0 * HID + c0], s0);
            atomicAdd(&agg[(size_t)(n0 + 1) * HID + c0], s1);
        }
    }

    if (xdelta) {   // layers 0..L-2 only: coord path + m feeds next layer
        __syncthreads();
        // ---- GEMM3 (transposed): D[j2][e] = cW1^T @ m^T
        // wave w: etile = w&3 (16 edges), jhalf = w>>2 (64 j2 rows)
        const int etile = w & 3, jhalf = w >> 2;
        f32x4 acc3[4] = {};
        {
            const int erow = etile * 16 + lr;
            const int eswz = (erow & 7) << 4;
            const char* mb0 = smem + MBASE + erow * 256 + ((lq * 16) ^ eswz);
            const char* mb1 = smem + MBASE + erow * 256 + ((lq * 16 + 64) ^ eswz);
#pragma unroll
            for (int kb2 = 0; kb2 < 2; ++kb2) {
                const short8 mf0 = *(const short8*)(mb0 + kb2 * 128);
                const short8 mf1 = *(const short8*)(mb1 + kb2 * 128);
#pragma unroll
                for (int jt = 0; jt < 4; ++jt) {
                    const short8 af0 = cw1p[((2 * kb2) * 8 + jhalf * 4 + jt) * 64 + lane];
                    const short8 af1 = cw1p[((2 * kb2 + 1) * 8 + jhalf * 4 + jt) * 64 + lane];
                    acc3[jt] = __builtin_amdgcn_mfma_f32_16x16x32_bf16(af0, mf0, acc3[jt], 0, 0, 0);
                    acc3[jt] = __builtin_amdgcn_mfma_f32_16x16x32_bf16(af1, mf1, acc3[jt], 0, 0, 0);
                }
            }
        }
        // ---- m -> global (bf16, row-contiguous from LDS)
        {
            const int s = t & 15, g = t >> 4;
#pragma unroll
            for (int j = 0; j < 2; ++j) {
                const int r = g + j * 32;
                const uint4 v = *(const uint4*)(smem + MBASE + r * 256 +
                                                ((s * 16) ^ ((r & 7) << 4)));
                *(uint4*)(ea + (size_t)(ebase + r) * EA_STRIDE + s * 8) = v;
            }
        }
        // ---- epilogue 3: per-lane dot over its 16 j2 rows, 2 shfl, 1 LDS write
        {
            float p = 0.0f;
#pragma unroll
            for (int jt = 0; jt < 4; ++jt)
#pragma unroll
                for (int reg = 0; reg < 4; ++reg) {
                    const int j2 = jhalf * 64 + jt * 16 + lq * 4 + reg;
                    p += silu_f(acc3[jt][reg] + cb1s[j2]) * cw2s[j2];
                }
            p += __shfl_xor(p, 16);
            p += __shfl_xor(p, 32);
            if (lane < 16) red[jhalf * 64 + etile * 16 + lane] = p;
        }
        __syncthreads();
        // ---- coord: c_e * (dx,dy,dz), segmented reduce over wave 0, 6 atomics
        if (t < 64) {
            const float c = red[t] + red[64 + t];
            const float cdx = c * dxs[t], cdy = c * dys[t], cdz = c * dzs[t];
            const bool in0 = (t < esplit);
            float a0x = in0 ? cdx : 0.0f, a1x = in0 ? 0.0f : cdx;
            float a0y = in0 ? cdy : 0.0f, a1y = in0 ? 0.0f : cdy;
            float a0z = in0 ? cdz : 0.0f, a1z = in0 ? 0.0f : cdz;
#pragma unroll
            for (int off = 1; off < 64; off <<= 1) {
                a0x += __shfl_xor(a0x, off); a1x += __shfl_xor(a1x, off);
                a0y += __shfl_xor(a0y, off); a1y += __shfl_xor(a1y, off);
                a0z += __shfl_xor(a0z, off); a1z += __shfl_xor(a1z, off);
            }
            if (t == 0) {
                atomicAdd(&xdelta[n0 * 3 + 0], a0x);
                atomicAdd(&xdelta[n0 * 3 + 1], a0y);
                atomicAdd(&xdelta[n0 * 3 + 2], a0z);
                atomicAdd(&xdelta[(n0 + 1) * 3 + 0], a1x);
                atomicAdd(&xdelta[(n0 + 1) * 3 + 1], a1y);
                atomicAdd(&xdelta[(n0 + 1) * 3 + 2], a1z);
            }
        }
    }
}

// node kernel: [h|agg] MLP (MFMA, residual) + agg re-zero + xdelta apply/re-zero
// + next-layer hr1b = hnew @ W1a + b1_next
__global__ __launch_bounds__(512, 4) void node_mfma_kernel(
    float* __restrict__ h_ws, unsigned short* __restrict__ h_bf,
    float* __restrict__ agg,
    const short8* __restrict__ nw1p, const float* __restrict__ nb1,
    const short8* __restrict__ nw2p, const float* __restrict__ nb2,
    const short8* __restrict__ w1a_next, const float* __restrict__ b1_next,
    float* __restrict__ hr1,
    const float* __restrict__ x_in, float* __restrict__ x_out,
    float* __restrict__ xdelta,
    float* __restrict__ out, const int write_out, const int do_coord)
{
    __shared__ __align__(16) char smem[16384];  // nin[16][512B] | hid@8192 | hnew@12288
    const int t = threadIdx.x;
    const int w = t >> 6, lane = t & 63, lq = lane >> 4, lr = lane & 15;
    const int nb = blockIdx.x * NPB;

    // ---- stage nin = [h | agg] (16 rows x 32 slots), zero agg
    {
        const int s = t & 31, g = t >> 5;       // g = row 0..15
        const int node = nb + g;
        const int swz = (g & 7) << 4;
        if (s < 16) {
            *(uint4*)(smem + g * 512 + ((s * 16) ^ swz)) =
                *(const uint4*)(h_bf + (size_t)node * HID + s * 8);
        } else {
            const int q = s - 16;
            float4* agg4 = (float4*)(agg + (size_t)node * HID);
            const float4 a0 = agg4[q * 2], a1 = agg4[q * 2 + 1];
            agg4[q * 2]     = float4{0, 0, 0, 0};
            agg4[q * 2 + 1] = float4{0, 0, 0, 0};
            uint4 v;
            v.x = pkbf(a0.x, a0.y);
            v.y = pkbf(a0.z, a0.w);
            v.z = pkbf(a1.x, a1.y);
            v.w = pkbf(a1.z, a1.w);
            *(uint4*)(smem + g * 512 + ((s * 16) ^ swz)) = v;
        }
    }
    // ---- xdelta apply + re-zero (elementwise; no gather)
    if (do_coord && t < NPB * 3) {
        const int n = nb + t / 3, d = t - (t / 3) * 3;
        const float xd = xdelta[n * 3 + d];
        x_out[n * 3 + d] = x_in[n * 3 + d] + xd * (1.0f / DEG);
        xdelta[n * 3 + d] = 0.0f;
    }
    __syncthreads();

    const int c0 = w * 16 + lr;

    // ---- GEMM1: nin(16x256) @ nW1
    f32x4 acc1 = {};
    {
        const int swz = (lr & 7) << 4;
        const char* b0 = smem + lr * 512 + ((lq * 16) ^ swz);
        const char* b1 = smem + lr * 512 + ((lq * 16 + 64) ^ swz);
#pragma unroll
        for (int kk2 = 0; kk2 < 4; ++kk2) {
            const short8 bf0 = nw1p[((2 * kk2) * 8 + w) * 64 + lane];
            const short8 bf1 = nw1p[((2 * kk2 + 1) * 8 + w) * 64 + lane];
            acc1 = __builtin_amdgcn_mfma_f32_16x16x32_bf16(
                *(const short8*)(b0 + kk2 * 128), bf0, acc1, 0, 0, 0);
            acc1 = __builtin_amdgcn_mfma_f32_16x16x32_bf16(
                *(const short8*)(b1 + kk2 * 128), bf1, acc1, 0, 0, 0);
        }
    }
    __syncthreads();
    {
        const float bb = nb1[c0];
#pragma unroll
        for (int reg = 0; reg < 4; ++reg) {
            const int r = lq * 4 + reg;
            const float v = silu_f(acc1[reg] + bb);
            *(unsigned short*)(smem + 8192 + r * 256 + ((c0 * 2) ^ ((r & 7) << 4))) = f2bf(v);
        }
    }
    __syncthreads();
    // ---- GEMM2: hid(16x128) @ nW2
    f32x4 acc2 = {};
    {
        const int swz = (lr & 7) << 4;
        const char* b0 = smem + 8192 + lr * 256 + ((lq * 16) ^ swz);
        const char* b1 = smem + 8192 + lr * 256 + ((lq * 16 + 64) ^ swz);
#pragma unroll
        for (int kk2 = 0; kk2 < 2; ++kk2) {
            const short8 bf0 = nw2p[((2 * kk2) * 8 + w) * 64 + lane];
            const short8 bf1 = nw2p[((2 * kk2 + 1) * 8 + w) * 64 + lane];
            acc2 = __builtin_amdgcn_mfma_f32_16x16x32_bf16(
                *(const short8*)(b0 + kk2 * 128), bf0, acc2, 0, 0, 0);
            acc2 = __builtin_amdgcn_mfma_f32_16x16x32_bf16(
                *(const short8*)(b1 + kk2 * 128), bf1, acc2, 0, 0, 0);
        }
    }
    // ---- epilogue 2: residual; write h (f32/bf16/out); stage hnew
    {
        const float bb = nb2[c0];
#pragma unroll
        for (int reg = 0; reg < 4; ++reg) {
            const int r = lq * 4 + reg;
            const size_t gi = (size_t)(nb + r) * HID + c0;
            const float hnew = h_ws[gi] + acc2[reg] + bb;
            h_ws[gi] = hnew;
            h_bf[gi] = f2bf(hnew);
            if (write_out) out[gi] = hnew;
            *(unsigned short*)(smem + 12288 + r * 256 + ((c0 * 2) ^ ((r & 7) << 4))) = f2bf(hnew);
        }
    }
    __syncthreads();
    // ---- hr1b for next layer: hnew(16x128) @ W1a_next + b1_next
    if (w1a_next) {
        f32x4 acch = {};
        const int swz = (lr & 7) << 4;
        const char* b0 = smem + 12288 + lr * 256 + ((lq * 16) ^ swz);
        const char* b1 = smem + 12288 + lr * 256 + ((lq * 16 + 64) ^ swz);
#pragma unroll
        for (int kk2 = 0; kk2 < 2; ++kk2) {
            const short8 bf0 = w1a_next[((2 * kk2) * 8 + w) * 64 + lane];
            const short8 bf1 = w1a_next[((2 * kk2 + 1) * 8 + w) * 64 + lane];
            acch = __builtin_amdgcn_mfma_f32_16x16x32_bf16(
                *(const short8*)(b0 + kk2 * 128), bf0, acch, 0, 0, 0);
            acch = __builtin_amdgcn_mfma_f32_16x16x32_bf16(
                *(const short8*)(b1 + kk2 * 128), bf1, acch, 0, 0, 0);
        }
        const float bb = b1_next[c0];
#pragma unroll
        for (int reg = 0; reg < 4; ++reg) {
            const int r = lq * 4 + reg;
            hr1[(size_t)(nb + r) * HID + c0] = acch[reg] + bb;
        }
    }
}

extern "C" void kernel_launch(void* const* d_in, const int* in_sizes, int n_in,
                              void* d_out, int out_size, void* d_ws, size_t ws_size,
                              hipStream_t stream)
{
    const float* h_in  = (const float*)d_in[0];
    const float* x_in  = (const float*)d_in[1];
    const float* ea0   = (const float*)d_in[4];
    const float* emb_w = (const float*)d_in[5];
    const float* emb_b = (const float*)d_in[6];
    const float* eW1   = (const float*)d_in[7];
    const float* eB1   = (const float*)d_in[8];
    const float* eW2   = (const float*)d_in[9];
    const float* eB2   = (const float*)d_in[10];
    const float* nW1   = (const float*)d_in[11];
    const float* nB1   = (const float*)d_in[12];
    const float* nW2   = (const float*)d_in[13];
    const float* nB2   = (const float*)d_in[14];
    const float* cW1   = (const float*)d_in[15];
    const float* cB1   = (const float*)d_in[16];
    const float* cW2   = (const float*)d_in[17];
    float* out = (float*)d_out;

    // bf16 edge features aliased over f32 edge_attr (256B used of each 512B row;
    // per-edge byte ranges coincide -> block-local in-place conversion, no race)
    unsigned short* ea_bf = (unsigned short*)d_in[4];

    char* p = (char*)d_ws;
    float* h_ws = (float*)p;                    p += (size_t)NNODES * HID * 4;
    unsigned short* h_bf = (unsigned short*)p;  p += (size_t)NNODES * HID * 2;
    float* agg  = (float*)p;                    p += (size_t)(NNODES + 1) * HID * 4;
    float* hr1  = (float*)p;                    p += (size_t)(NNODES + 1) * HID * 4;
    float* x_a  = (float*)p;                    p += NNODES * 3 * 4 + 16;
    float* x_b  = (float*)p;                    p += NNODES * 3 * 4 + 16;
    float* xdelta = (float*)p;                  p += NNODES * 3 * 4 + 16;
    unsigned short* w1p  = (unsigned short*)p;  p += (size_t)NLAYER * 8 * 8 * 64 * 8 * 2;
    unsigned short* w1a  = (unsigned short*)p;  p += (size_t)NLAYER * 4 * 8 * 64 * 8 * 2;
    unsigned short* w2p  = (unsigned short*)p;  p += (size_t)NLAYER * 4 * 8 * 64 * 8 * 2;
    unsigned short* cw1p = (unsigned short*)p;  p += (size_t)NLAYER * 4 * 8 * 64 * 8 * 2;
    unsigned short* nw1p = (unsigned short*)p;  p += (size_t)NLAYER * 8 * 8 * 64 * 8 * 2;
    unsigned short* nw2p = (unsigned short*)p;  p += (size_t)NLAYER * 4 * 8 * 64 * 8 * 2;

    const int SL8 = 8 * 8 * 64 * 8;
    const int SL4 = 4 * 8 * 64 * 8;

    pack_all_kernel<<<1024, 64, 0, stream>>>(eW1, eW2, cW1, nW1, nW2,
                                             w1p, w1a, w2p, cw1p, nw1p, nw2p);

    embed_kernel<<<NNODES, HID, 0, stream>>>(h_in, emb_w, emb_b, eW1, eB1,
                                             h_ws, h_bf, hr1, agg, xdelta, x_in, x_a);

    float* xc = x_a;
    float* xn = x_b;
    for (int i = 0; i < NLAYER; ++i) {
        const int last = (i == NLAYER - 1);
        edge_mfma_kernel<<<EBLOCKS, 512, 0, stream>>>(
            h_bf, xc, ea0, ea_bf, (i == 0) ? 1 : 0, hr1,
            (const short8*)(w1p + (size_t)i * SL8),
            eW1 + ((size_t)i * K1 + 256) * HID,
            (const short8*)(w2p + (size_t)i * SL4), eB2 + i * HID,
            (const short8*)(cw1p + (size_t)i * SL4), cB1 + i * HID,
            cW2 + (size_t)i * HID,
            last ? nullptr : xdelta, agg);
        node_mfma_kernel<<<NBLOCKS, 512, 0, stream>>>(
            h_ws, h_bf, agg,
            (const short8*)(nw1p + (size_t)i * SL8), nB1 + i * HID,
            (const short8*)(nw2p + (size_t)i * SL4), nB2 + i * HID,
            last ? (const short8*)nullptr : (const short8*)(w1a + (size_t)(i + 1) * SL4),
            last ? nullptr : (eB1 + (size_t)(i + 1) * HID),
            hr1, xc, xn, xdelta,
            out, last ? 1 : 0, last ? 0 : 1);
        float* tmp = xc; xc = xn; xn = tmp;
    }
}